// Round 8
// baseline (109.075 us; speedup 1.0000x reference)
//
#include <hip/hip_runtime.h>
#include <hip/hip_bf16.h>

// Problem constants
#define B_    64
#define C_    64
#define N_    22
#define T_    1024
#define O_    64
#define KTOT  1408      // C_*N_
#define KSTEPS 44       // KTOT/32
#define KHTILES 22      // tiles per k-half

typedef __bf16 bf16x8 __attribute__((ext_vector_type(8)));
typedef float  f32x4  __attribute__((ext_vector_type(4)));

typedef __attribute__((address_space(1))) float f32_g;
typedef __attribute__((address_space(3))) float f32_l;

// ---------------------------------------------------------------------------
// prep_all: grid 256 = 64 o x 4 kq (validated since R5).
// ---------------------------------------------------------------------------
__global__ __launch_bounds__(256) void prep_all(
    const float* __restrict__ adjp,
    const float* __restrict__ chebw,   // [3][64][64]
    const float* __restrict__ chebb,   // [64]
    const float* __restrict__ aggw,    // [64][64][22]
    const float* __restrict__ aggb,    // [64]
    __bf16* __restrict__ Mfrag,        // [176*512]
    float* __restrict__ constv)        // [64]
{
    const int o   = blockIdx.x >> 2;
    const int kq  = blockIdx.x & 3;
    const int tid = threadIdx.x;
    __shared__ float sm[484];
    __shared__ float c2[484];
    __shared__ float dis[22];
    __shared__ float aggs[KTOT];
    __shared__ float F1[KTOT];
    __shared__ float F2[KTOT];
    __shared__ float red[256];

    for (int e = tid; e < 484; e += 256) {
        int i = e / 22, j = e - i * 22;
        float a = 0.5f * (1.f / (1.f + expf(-adjp[i * 22 + j])) +
                          1.f / (1.f + expf(-adjp[j * 22 + i])));
        c2[e] = (i == j) ? 0.f : a;
    }
    for (int e = tid; e < KTOT; e += 256) aggs[e] = aggw[o * KTOT + e];
    __syncthreads();
    if (tid < 22) {
        float d = 0.f;
        for (int n = 0; n < 22; ++n) d += c2[tid * 22 + n];
        dis[tid] = rsqrtf(d);
    }
    __syncthreads();
    for (int e = tid; e < 484; e += 256) {
        int i = e / 22, j = e - i * 22;
        sm[e] = -dis[i] * c2[e] * dis[j];
    }
    __syncthreads();
    for (int e = tid; e < 484; e += 256) {
        int i = e / 22, j = e - i * 22;
        float acc = 0.f;
        for (int n = 0; n < 22; ++n) acc += sm[i * 22 + n] * sm[n * 22 + j];
        c2[e] = 2.f * acc - (i == j ? 1.f : 0.f);
    }
    __syncthreads();
    for (int e = tid; e < KTOT; e += 256) {
        int cp = e / 22, v = e - cp * 22;
        float a1 = 0.f, a2 = 0.f;
        for (int n = 0; n < 22; ++n) {
            float w = aggs[cp * 22 + n];
            a1 += w * sm[n * 22 + v];
            a2 += w * c2[n * 22 + v];
        }
        F1[e] = a1;
        F2[e] = a2;
    }
    if (kq == 0) {
        float p = 0.f;
        for (int e = tid; e < KTOT; e += 256) p += aggs[e] * chebb[e / 22];
        red[tid] = p;
    }
    __syncthreads();
    if (kq == 0) {
#pragma unroll
        for (int st = 128; st > 0; st >>= 1) {
            if (tid < st) red[tid] += red[tid + st];
            __syncthreads();
        }
        if (tid == 0) constv[o] = red[0] + aggb[o];
    }

    const int fo = o >> 4, l15 = o & 15;
    const int kend = (kq + 1) * 352;
    for (int k = kq * 352 + tid; k < kend; k += 256) {
        int c = k / 22, v = k - c * 22;
        const float* w0 = chebw + c * 64;
        float a0 = 0.f, a1 = 0.f, a2 = 0.f;
        for (int cp = 0; cp < 64; ++cp) {
            int idx = cp * 22 + v;
            a0 += w0[cp] * aggs[idx];
            a1 += w0[4096 + cp] * F1[idx];
            a2 += w0[8192 + cp] * F2[idx];
        }
        int ks = k >> 5, r = k & 31, lhi = r >> 3, j = r & 7;
        Mfrag[(((ks * 4 + fo) * 64) + lhi * 16 + l15) * 8 + j] = (__bf16)(a0 + a1 + a2);
    }
}

// ---------------------------------------------------------------------------
// main GEMM (k-split): grid 256 = 64 b x 2 th x 2 kh. Block computes
// part[kh][b][64 o][t-half of 512] over its 22 k-tiles.
// R6's verified inner structure: 2 x 64 KB LDS buffers [32 k][512 t] fp32,
// 16 waves, rows fetched as 2 back-to-back 1 KB instrs (2 KB granularity),
// chunk^kg source-side swizzle (read uses same XOR -> 2-way free),
// counted WAITV(4) steady (never 0 in loop).
// ---------------------------------------------------------------------------
#define WAITV(N) asm volatile("s_waitcnt vmcnt(" #N ")" ::: "memory")
#define BARR do { __builtin_amdgcn_s_barrier(); __builtin_amdgcn_sched_barrier(0); } while (0)

__global__ __launch_bounds__(1024, 4) void gemm_main(
    const float* __restrict__ x,
    const __bf16* __restrict__ Mfrag,
    float* __restrict__ part)          // [2][64][64][1024]
{
    __shared__ float lds[2 * 16384];   // 2 x [32][512] fp32 = 128 KB

    // bijective XCD swizzle (256 % 8 == 0)
    const int bid  = ((blockIdx.x & 7) << 5) | (blockIdx.x >> 3);
    const int kh   = bid & 1;
    const int th   = (bid >> 1) & 1;
    const int b    = bid >> 2;
    const int wave = threadIdx.x >> 6;   // 0..15
    const int lane = threadIdx.x & 63;
    const int tcol = lane & 15;
    const int kg   = lane >> 4;
    const int cq   = lane >> 2;          // 64B chunk handled by this lane
    const int ce   = lane & 3;           // 16B sub-chunk

    const size_t xbase = (size_t)b * ((size_t)KTOT * T_)
                       + (size_t)kh * (704 * T_) + (size_t)th * 512;
    const int kbase = kh * KHTILES;      // absolute k-tile base for Mfrag

    // read: lane (kg,tcol), j: needs x[k=kg*8+j][t=wave*32+m*16+tcol]
    // global t-chunk G = wave*2+m stored at LDS chunk G ^ kg
    const int rd0 = (kg * 8) * 512 + ((((wave << 1) | 0) ^ kg) << 4) + tcol;
    const int rd1 = (kg * 8) * 512 + ((((wave << 1) | 1) ^ kg) << 4) + tcol;

    const __bf16* mf = Mfrag + (size_t)lane * 8;

    f32x4 acc[2][4];
#pragma unroll
    for (int m = 0; m < 2; ++m)
#pragma unroll
        for (int fo = 0; fo < 4; ++fo) acc[m][fo] = (f32x4){0.f, 0.f, 0.f, 0.f};

    // STAGE: wave covers rows 2w, 2w+1; instr h: row 2w+(h>>1), KB-half h&1.
    auto STAGE = [&](int ks, float* buf) {
#pragma unroll
        for (int h = 0; h < 4; ++h) {
            const int r  = 2 * wave + (h >> 1);
            const int s  = (r >> 3) & 3;
            const int cL = (h & 1) * 16 + cq;        // LDS chunk this lane fills
            const int g  = cL ^ s;                   // global chunk to fetch
            const float* src = x + xbase + (size_t)(ks * 32 + r) * T_ + g * 16 + ce * 4;
            float* dst = buf + r * 512 + (h & 1) * 256;   // wave-uniform base
            __builtin_amdgcn_global_load_lds((const f32_g*)src, (f32_l*)dst, 16, 0, 0);
        }
    };
    auto PREFA = [&](bf16x8* dst, int ks) {
        const __bf16* p = mf + (size_t)(kbase + ks) * 2048;
#pragma unroll
        for (int fo = 0; fo < 4; ++fo)
            dst[fo] = *reinterpret_cast<const bf16x8*>(p + fo * 512);
    };
    auto COMPUTE = [&](const bf16x8* a, const float* buf) {
#pragma unroll
        for (int m = 0; m < 2; ++m) {
            const int rb = m ? rd1 : rd0;
            float v[8];
#pragma unroll
            for (int j = 0; j < 8; ++j) v[j] = buf[rb + j * 512];
            bf16x8 bx;
#pragma unroll
            for (int j = 0; j < 8; ++j) bx[j] = (__bf16)v[j];
#pragma unroll
            for (int fo = 0; fo < 4; ++fo)
                acc[m][fo] = __builtin_amdgcn_mfma_f32_16x16x32_bf16(a[fo], bx, acc[m][fo], 0, 0, 0);
        }
    };

    float* const b0 = lds;
    float* const b1 = lds + 16384;
    bf16x8 ac[4], an[4];

    // ---- prologue: chronological VMEM order [S(0), A(0), S(1)] ----
    STAGE(0, b0);
    PREFA(ac, 0);
    STAGE(1, b1);

    // ---- main loop: tiles 0..19 (pairs; even->b0, odd->b1) ----
    // iter t: WAITV(4) drains {S(t),A(t)}, keeps S(t+1); barrier;
    //         PREFA(t+1); COMPUTE(t); barrier (reads done); STAGE(t+2).
    for (int t = 0; t < 20; t += 2) {
        WAITV(4); BARR; PREFA(an, t + 1); COMPUTE(ac, b0); BARR; STAGE(t + 2, b0);
        WAITV(4); BARR; PREFA(ac, t + 2); COMPUTE(an, b1); BARR; STAGE(t + 3, b1);
    }
    // ---- tile 20 ----
    WAITV(4); BARR; PREFA(an, 21); COMPUTE(ac, b0); BARR;
    // ---- tile 21 ----
    WAITV(0); BARR; COMPUTE(an, b1);

    // ---- store partials: part[kh][b][o][th*512 + wave*32 + m*16 + tcol]
    float* pp = part + (((size_t)kh * 64 + b) * 64) * T_
              + th * 512 + wave * 32 + tcol;
#pragma unroll
    for (int m = 0; m < 2; ++m)
#pragma unroll
        for (int fo = 0; fo < 4; ++fo)
#pragma unroll
            for (int rr = 0; rr < 4; ++rr) {
                int o = fo * 16 + kg * 4 + rr;
                pp[(size_t)o * T_ + m * 16] = acc[m][fo][rr];
            }
}

// ---------------------------------------------------------------------------
// reduce: y = part[0] + part[1] + constv[o].  64*64*1024 floats.
// 1024 blocks x 256 threads, 16 consecutive floats (4 x f32x4) per thread.
// ---------------------------------------------------------------------------
__global__ __launch_bounds__(256) void reduce_k(
    const float* __restrict__ part,    // [2][64][64][1024]
    const float* __restrict__ constv,  // [64]
    float* __restrict__ y)             // [64][64][1024]
{
    const size_t f = ((size_t)blockIdx.x * 256 + threadIdx.x) * 16;
    const int o = (int)((f >> 10) & 63);
    const float cv = constv[o];
    const float* p0 = part + f;
    const float* p1 = part + (size_t)64 * 64 * 1024 + f;
    float* yo = y + f;
#pragma unroll
    for (int q = 0; q < 4; ++q) {
        f32x4 a = *reinterpret_cast<const f32x4*>(p0 + q * 4);
        f32x4 c = *reinterpret_cast<const f32x4*>(p1 + q * 4);
#pragma unroll
        for (int e = 0; e < 4; ++e) a[e] = a[e] + c[e] + cv;
        *reinterpret_cast<f32x4*>(yo + q * 4) = a;
    }
}

// ---------------------------------------------------------------------------
extern "C" void kernel_launch(void* const* d_in, const int* in_sizes, int n_in,
                              void* d_out, int out_size, void* d_ws, size_t ws_size,
                              hipStream_t stream)
{
    (void)in_sizes; (void)n_in; (void)out_size; (void)ws_size;
    const float* x     = (const float*)d_in[0];
    const float* adjp  = (const float*)d_in[1];
    const float* chebw = (const float*)d_in[2];
    const float* chebb = (const float*)d_in[3];
    const float* aggw  = (const float*)d_in[4];
    const float* aggb  = (const float*)d_in[5];
    float* y = (float*)d_out;

    char* ws = (char*)d_ws;
    float*  constv = (float*)(ws);                 // 64 floats
    __bf16* Mfrag  = (__bf16*)(ws + 4096);         // 90112 bf16 (180224 B)
    float*  part   = (float*)(ws + 262144);        // 2*64*64*1024 fp32 = 32 MB

    hipLaunchKernelGGL(prep_all, dim3(256), dim3(256), 0, stream,
                       adjp, chebw, chebb, aggw, aggb, Mfrag, constv);
    hipLaunchKernelGGL(gemm_main, dim3(256), dim3(1024), 0, stream,
                       x, Mfrag, part);
    hipLaunchKernelGGL(reduce_k, dim3(1024), dim3(256), 0, stream,
                       part, constv, y);
}

// Round 9
// 79.051 us; speedup vs baseline: 1.3798x; 1.3798x over previous
//
#include <hip/hip_runtime.h>
#include <hip/hip_bf16.h>

// Problem constants
#define B_    64
#define C_    64
#define N_    22
#define T_    1024
#define O_    64
#define KTOT  1408      // C_*N_
#define KSTEPS 44       // KTOT/32

typedef __bf16 bf16x8 __attribute__((ext_vector_type(8)));
typedef float  f32x4  __attribute__((ext_vector_type(4)));

typedef __attribute__((address_space(1))) float f32_g;
typedef __attribute__((address_space(3))) float f32_l;

// ---------------------------------------------------------------------------
// prep_all: grid 256 = 64 o x 4 kq (validated since R5).
// ---------------------------------------------------------------------------
__global__ __launch_bounds__(256) void prep_all(
    const float* __restrict__ adjp,
    const float* __restrict__ chebw,   // [3][64][64]
    const float* __restrict__ chebb,   // [64]
    const float* __restrict__ aggw,    // [64][64][22]
    const float* __restrict__ aggb,    // [64]
    __bf16* __restrict__ Mfrag,        // [176*512]
    float* __restrict__ constv)        // [64]
{
    const int o   = blockIdx.x >> 2;
    const int kq  = blockIdx.x & 3;
    const int tid = threadIdx.x;
    __shared__ float sm[484];
    __shared__ float c2[484];
    __shared__ float dis[22];
    __shared__ float aggs[KTOT];
    __shared__ float F1[KTOT];
    __shared__ float F2[KTOT];
    __shared__ float red[256];

    for (int e = tid; e < 484; e += 256) {
        int i = e / 22, j = e - i * 22;
        float a = 0.5f * (1.f / (1.f + expf(-adjp[i * 22 + j])) +
                          1.f / (1.f + expf(-adjp[j * 22 + i])));
        c2[e] = (i == j) ? 0.f : a;
    }
    for (int e = tid; e < KTOT; e += 256) aggs[e] = aggw[o * KTOT + e];
    __syncthreads();
    if (tid < 22) {
        float d = 0.f;
        for (int n = 0; n < 22; ++n) d += c2[tid * 22 + n];
        dis[tid] = rsqrtf(d);
    }
    __syncthreads();
    for (int e = tid; e < 484; e += 256) {
        int i = e / 22, j = e - i * 22;
        sm[e] = -dis[i] * c2[e] * dis[j];
    }
    __syncthreads();
    for (int e = tid; e < 484; e += 256) {
        int i = e / 22, j = e - i * 22;
        float acc = 0.f;
        for (int n = 0; n < 22; ++n) acc += sm[i * 22 + n] * sm[n * 22 + j];
        c2[e] = 2.f * acc - (i == j ? 1.f : 0.f);
    }
    __syncthreads();
    for (int e = tid; e < KTOT; e += 256) {
        int cp = e / 22, v = e - cp * 22;
        float a1 = 0.f, a2 = 0.f;
        for (int n = 0; n < 22; ++n) {
            float w = aggs[cp * 22 + n];
            a1 += w * sm[n * 22 + v];
            a2 += w * c2[n * 22 + v];
        }
        F1[e] = a1;
        F2[e] = a2;
    }
    if (kq == 0) {
        float p = 0.f;
        for (int e = tid; e < KTOT; e += 256) p += aggs[e] * chebb[e / 22];
        red[tid] = p;
    }
    __syncthreads();
    if (kq == 0) {
#pragma unroll
        for (int st = 128; st > 0; st >>= 1) {
            if (tid < st) red[tid] += red[tid + st];
            __syncthreads();
        }
        if (tid == 0) constv[o] = red[0] + aggb[o];
    }

    const int fo = o >> 4, l15 = o & 15;
    const int kend = (kq + 1) * 352;
    for (int k = kq * 352 + tid; k < kend; k += 256) {
        int c = k / 22, v = k - c * 22;
        const float* w0 = chebw + c * 64;
        float a0 = 0.f, a1 = 0.f, a2 = 0.f;
        for (int cp = 0; cp < 64; ++cp) {
            int idx = cp * 22 + v;
            a0 += w0[cp] * aggs[idx];
            a1 += w0[4096 + cp] * F1[idx];
            a2 += w0[8192 + cp] * F2[idx];
        }
        int ks = k >> 5, r = k & 31, lhi = r >> 3, j = r & 7;
        Mfrag[(((ks * 4 + fo) * 64) + lhi * 16 + l15) * 8 + j] = (__bf16)(a0 + a1 + a2);
    }
}

// ---------------------------------------------------------------------------
// main GEMM: EXACT R4 structure (champion, 98.7 us): 256 blocks = 64b x 4tq,
// t-tile 256, 512 threads (8 waves), 3 x 32 KB LDS buffers, stage distance 2,
// counted WAITV(4) (never 0 in main loop), source-side chunk-XOR swizzle.
// ONLY change vs R4: NT cache policy (aux=2) on the x global_load_lds
// (stream-once data: no L2/MALL allocation) and nontemporal y stores.
// ---------------------------------------------------------------------------
#define WAITV(N) asm volatile("s_waitcnt vmcnt(" #N ")" ::: "memory")
#define BARR do { __builtin_amdgcn_s_barrier(); __builtin_amdgcn_sched_barrier(0); } while (0)

__global__ __launch_bounds__(512, 2) void gemm_main(
    const float* __restrict__ x,
    const __bf16* __restrict__ Mfrag,
    const float* __restrict__ constv,
    float* __restrict__ y)
{
    __shared__ float lds[3 * 8192];   // 3 x [32 k][256 t] fp32 = 96 KB

    // XCD swizzle: 256 blocks -> 32 per XCD (bijective, 256 % 8 == 0)
    const int bid  = ((blockIdx.x & 7) << 5) | (blockIdx.x >> 3);
    const int b    = bid >> 2;
    const int tq   = bid & 3;
    const int wave = threadIdx.x >> 6;   // 0..7
    const int lane = threadIdx.x & 63;
    const int tcol = lane & 15;
    const int kg   = lane >> 4;

    const size_t xbase = (size_t)b * ((size_t)KTOT * T_) + (size_t)tq * 256;

    // read addressing: lane (kg,tcol), j: needs x[k=kg*8+j][t=wave*32+m*16+tcol]
    // global t-chunk G = wave*2+m stored at LDS chunk G ^ (kg&1)
    const int rd0 = (kg * 8) * 256 + ((((wave << 1) | 0) ^ (kg & 1)) << 4) + tcol;
    const int rd1 = (kg * 8) * 256 + ((((wave << 1) | 1) ^ (kg & 1)) << 4) + tcol;

    const __bf16* mf = Mfrag + (size_t)lane * 8;

    f32x4 acc[2][4];
#pragma unroll
    for (int m = 0; m < 2; ++m)
#pragma unroll
        for (int fo = 0; fo < 4; ++fo) acc[m][fo] = (f32x4){0.f, 0.f, 0.f, 0.f};

    // STAGE: wave stages rows wave*4+q (1 KB each, one gload_lds per row).
    // LDS dest wave-uniform + lane*16B (linear); source pre-swizzled.
    // aux=2 -> NT (no temporal reuse): x is streamed exactly once.
    auto STAGE = [&](int ks, float* buf) {
#pragma unroll
        for (int q = 0; q < 4; ++q) {
            const int r = wave * 4 + q;
            const int s = (r >> 3) & 1;
            const int g = ((lane >> 2) ^ s);
            const float* src = x + xbase + (size_t)(ks * 32 + r) * T_
                             + g * 16 + (lane & 3) * 4;
            float* dst = buf + r * 256;              // wave-uniform base
            __builtin_amdgcn_global_load_lds((const f32_g*)src, (f32_l*)dst, 16, 0, 2);
        }
    };
    auto PREFA = [&](bf16x8* dst, int ks) {
        const __bf16* p = mf + (size_t)ks * 2048;
#pragma unroll
        for (int fo = 0; fo < 4; ++fo)
            dst[fo] = *reinterpret_cast<const bf16x8*>(p + fo * 512);
    };
    auto COMPUTE = [&](const bf16x8* a, const float* buf) {
#pragma unroll
        for (int m = 0; m < 2; ++m) {
            const int rb = m ? rd1 : rd0;
            float v[8];
#pragma unroll
            for (int j = 0; j < 8; ++j) v[j] = buf[rb + j * 256];
            bf16x8 bx;
#pragma unroll
            for (int j = 0; j < 8; ++j) bx[j] = (__bf16)v[j];
#pragma unroll
            for (int fo = 0; fo < 4; ++fo)
                acc[m][fo] = __builtin_amdgcn_mfma_f32_16x16x32_bf16(a[fo], bx, acc[m][fo], 0, 0, 0);
        }
    };

    float* const b0 = lds;
    float* const b1 = lds + 8192;
    float* const b2 = lds + 16384;
    bf16x8 ac[4], an[4];

    // ---- prologue: chronological VMEM order [S0(4), A0(4), S1(4)] ----
    STAGE(0, b0);
    PREFA(ac, 0);
    STAGE(1, b1);

    // ---- main loop: tiles 0..41 ----
    // tile j: WAITV(4) drains {S(j),A(j)}, keeps S(j+1); barrier;
    //         PREFA(j+1); STAGE(j+2); COMPUTE(j).
    for (int i = 0; i < 42; i += 6) {
        WAITV(4); BARR; PREFA(an, i + 1); STAGE(i + 2, b2); COMPUTE(ac, b0);
        WAITV(4); BARR; PREFA(ac, i + 2); STAGE(i + 3, b0); COMPUTE(an, b1);
        WAITV(4); BARR; PREFA(an, i + 3); STAGE(i + 4, b1); COMPUTE(ac, b2);
        WAITV(4); BARR; PREFA(ac, i + 4); STAGE(i + 5, b2); COMPUTE(an, b0);
        WAITV(4); BARR; PREFA(an, i + 5); STAGE(i + 6, b0); COMPUTE(ac, b1);
        WAITV(4); BARR; PREFA(ac, i + 6); STAGE(i + 7, b1); COMPUTE(an, b2);
    }

    // ---- tail: tiles 42 (b0, ac), 43 (b1, an) ----
    WAITV(4); BARR; PREFA(an, 43); COMPUTE(ac, b0);
    WAITV(0); BARR; COMPUTE(an, b1);

    // ---- store (nontemporal): o = fo*16+kg*4+rr, t = tq*256+wave*32+m*16+tcol
    float* yp = y + (size_t)b * (O_ * T_) + tq * 256 + wave * 32 + tcol;
#pragma unroll
    for (int m = 0; m < 2; ++m)
#pragma unroll
        for (int fo = 0; fo < 4; ++fo)
#pragma unroll
            for (int rr = 0; rr < 4; ++rr) {
                int o = fo * 16 + kg * 4 + rr;
                __builtin_nontemporal_store(acc[m][fo][rr] + constv[o],
                                            yp + (size_t)o * T_ + m * 16);
            }
}

// ---------------------------------------------------------------------------
extern "C" void kernel_launch(void* const* d_in, const int* in_sizes, int n_in,
                              void* d_out, int out_size, void* d_ws, size_t ws_size,
                              hipStream_t stream)
{
    (void)in_sizes; (void)n_in; (void)out_size; (void)ws_size;
    const float* x     = (const float*)d_in[0];
    const float* adjp  = (const float*)d_in[1];
    const float* chebw = (const float*)d_in[2];
    const float* chebb = (const float*)d_in[3];
    const float* aggw  = (const float*)d_in[4];
    const float* aggb  = (const float*)d_in[5];
    float* y = (float*)d_out;

    char* ws = (char*)d_ws;
    float*  constv = (float*)(ws);                 // 64 floats
    __bf16* Mfrag  = (__bf16*)(ws + 4096);         // 90112 bf16 (180224 B)

    hipLaunchKernelGGL(prep_all, dim3(256), dim3(256), 0, stream,
                       adjp, chebw, chebb, aggw, aggb, Mfrag, constv);
    hipLaunchKernelGGL(gemm_main, dim3(256), dim3(512), 0, stream,
                       x, Mfrag, constv, y);
}

// Round 10
// 78.820 us; speedup vs baseline: 1.3838x; 1.0029x over previous
//
#include <hip/hip_runtime.h>
#include <hip/hip_bf16.h>

// Problem constants
#define B_    64
#define C_    64
#define N_    22
#define T_    1024
#define O_    64
#define KTOT  1408      // C_*N_
#define KSTEPS 44       // KTOT/32

typedef __bf16 bf16x8 __attribute__((ext_vector_type(8)));
typedef float  f32x4  __attribute__((ext_vector_type(4)));

typedef __attribute__((address_space(1))) float f32_g;
typedef __attribute__((address_space(3))) float f32_l;

// ---------------------------------------------------------------------------
// prep_all: grid 256 = 64 o x 4 kq (validated since R5).
// ---------------------------------------------------------------------------
__global__ __launch_bounds__(256) void prep_all(
    const float* __restrict__ adjp,
    const float* __restrict__ chebw,   // [3][64][64]
    const float* __restrict__ chebb,   // [64]
    const float* __restrict__ aggw,    // [64][64][22]
    const float* __restrict__ aggb,    // [64]
    __bf16* __restrict__ Mfrag,        // [176*512]
    float* __restrict__ constv)        // [64]
{
    const int o   = blockIdx.x >> 2;
    const int kq  = blockIdx.x & 3;
    const int tid = threadIdx.x;
    __shared__ float sm[484];
    __shared__ float c2[484];
    __shared__ float dis[22];
    __shared__ float aggs[KTOT];
    __shared__ float F1[KTOT];
    __shared__ float F2[KTOT];
    __shared__ float red[256];

    for (int e = tid; e < 484; e += 256) {
        int i = e / 22, j = e - i * 22;
        float a = 0.5f * (1.f / (1.f + expf(-adjp[i * 22 + j])) +
                          1.f / (1.f + expf(-adjp[j * 22 + i])));
        c2[e] = (i == j) ? 0.f : a;
    }
    for (int e = tid; e < KTOT; e += 256) aggs[e] = aggw[o * KTOT + e];
    __syncthreads();
    if (tid < 22) {
        float d = 0.f;
        for (int n = 0; n < 22; ++n) d += c2[tid * 22 + n];
        dis[tid] = rsqrtf(d);
    }
    __syncthreads();
    for (int e = tid; e < 484; e += 256) {
        int i = e / 22, j = e - i * 22;
        sm[e] = -dis[i] * c2[e] * dis[j];
    }
    __syncthreads();
    for (int e = tid; e < 484; e += 256) {
        int i = e / 22, j = e - i * 22;
        float acc = 0.f;
        for (int n = 0; n < 22; ++n) acc += sm[i * 22 + n] * sm[n * 22 + j];
        c2[e] = 2.f * acc - (i == j ? 1.f : 0.f);
    }
    __syncthreads();
    for (int e = tid; e < KTOT; e += 256) {
        int cp = e / 22, v = e - cp * 22;
        float a1 = 0.f, a2 = 0.f;
        for (int n = 0; n < 22; ++n) {
            float w = aggs[cp * 22 + n];
            a1 += w * sm[n * 22 + v];
            a2 += w * c2[n * 22 + v];
        }
        F1[e] = a1;
        F2[e] = a2;
    }
    if (kq == 0) {
        float p = 0.f;
        for (int e = tid; e < KTOT; e += 256) p += aggs[e] * chebb[e / 22];
        red[tid] = p;
    }
    __syncthreads();
    if (kq == 0) {
#pragma unroll
        for (int st = 128; st > 0; st >>= 1) {
            if (tid < st) red[tid] += red[tid + st];
            __syncthreads();
        }
        if (tid == 0) constv[o] = red[0] + aggb[o];
    }

    const int fo = o >> 4, l15 = o & 15;
    const int kend = (kq + 1) * 352;
    for (int k = kq * 352 + tid; k < kend; k += 256) {
        int c = k / 22, v = k - c * 22;
        const float* w0 = chebw + c * 64;
        float a0 = 0.f, a1 = 0.f, a2 = 0.f;
        for (int cp = 0; cp < 64; ++cp) {
            int idx = cp * 22 + v;
            a0 += w0[cp] * aggs[idx];
            a1 += w0[4096 + cp] * F1[idx];
            a2 += w0[8192 + cp] * F2[idx];
        }
        int ks = k >> 5, r = k & 31, lhi = r >> 3, j = r & 7;
        Mfrag[(((ks * 4 + fo) * 64) + lhi * 16 + l15) * 8 + j] = (__bf16)(a0 + a1 + a2);
    }
}

// ---------------------------------------------------------------------------
// main GEMM: EXACT R9 structure (champion, 79.0 us). Single change:
// x loads use aux = NT|SC1 = 18 (stream-through at BOTH L2 and MALL)
// instead of aux = 2 (NT at near level only).
// ---------------------------------------------------------------------------
#define WAITV(N) asm volatile("s_waitcnt vmcnt(" #N ")" ::: "memory")
#define BARR do { __builtin_amdgcn_s_barrier(); __builtin_amdgcn_sched_barrier(0); } while (0)

__global__ __launch_bounds__(512, 2) void gemm_main(
    const float* __restrict__ x,
    const __bf16* __restrict__ Mfrag,
    const float* __restrict__ constv,
    float* __restrict__ y)
{
    __shared__ float lds[3 * 8192];   // 3 x [32 k][256 t] fp32 = 96 KB

    // XCD swizzle: 256 blocks -> 32 per XCD (bijective, 256 % 8 == 0)
    const int bid  = ((blockIdx.x & 7) << 5) | (blockIdx.x >> 3);
    const int b    = bid >> 2;
    const int tq   = bid & 3;
    const int wave = threadIdx.x >> 6;   // 0..7
    const int lane = threadIdx.x & 63;
    const int tcol = lane & 15;
    const int kg   = lane >> 4;

    const size_t xbase = (size_t)b * ((size_t)KTOT * T_) + (size_t)tq * 256;

    // read addressing: lane (kg,tcol), j: needs x[k=kg*8+j][t=wave*32+m*16+tcol]
    // global t-chunk G = wave*2+m stored at LDS chunk G ^ (kg&1)
    const int rd0 = (kg * 8) * 256 + ((((wave << 1) | 0) ^ (kg & 1)) << 4) + tcol;
    const int rd1 = (kg * 8) * 256 + ((((wave << 1) | 1) ^ (kg & 1)) << 4) + tcol;

    const __bf16* mf = Mfrag + (size_t)lane * 8;

    f32x4 acc[2][4];
#pragma unroll
    for (int m = 0; m < 2; ++m)
#pragma unroll
        for (int fo = 0; fo < 4; ++fo) acc[m][fo] = (f32x4){0.f, 0.f, 0.f, 0.f};

    // STAGE: wave stages rows wave*4+q (1 KB each, one gload_lds per row).
    // LDS dest wave-uniform + lane*16B (linear); source pre-swizzled.
    // aux = 18 = NT|SC1 -> non-temporal at L2 AND MALL (x streamed once).
    auto STAGE = [&](int ks, float* buf) {
#pragma unroll
        for (int q = 0; q < 4; ++q) {
            const int r = wave * 4 + q;
            const int s = (r >> 3) & 1;
            const int g = ((lane >> 2) ^ s);
            const float* src = x + xbase + (size_t)(ks * 32 + r) * T_
                             + g * 16 + (lane & 3) * 4;
            float* dst = buf + r * 256;              // wave-uniform base
            __builtin_amdgcn_global_load_lds((const f32_g*)src, (f32_l*)dst, 16, 0, 18);
        }
    };
    auto PREFA = [&](bf16x8* dst, int ks) {
        const __bf16* p = mf + (size_t)ks * 2048;
#pragma unroll
        for (int fo = 0; fo < 4; ++fo)
            dst[fo] = *reinterpret_cast<const bf16x8*>(p + fo * 512);
    };
    auto COMPUTE = [&](const bf16x8* a, const float* buf) {
#pragma unroll
        for (int m = 0; m < 2; ++m) {
            const int rb = m ? rd1 : rd0;
            float v[8];
#pragma unroll
            for (int j = 0; j < 8; ++j) v[j] = buf[rb + j * 256];
            bf16x8 bx;
#pragma unroll
            for (int j = 0; j < 8; ++j) bx[j] = (__bf16)v[j];
#pragma unroll
            for (int fo = 0; fo < 4; ++fo)
                acc[m][fo] = __builtin_amdgcn_mfma_f32_16x16x32_bf16(a[fo], bx, acc[m][fo], 0, 0, 0);
        }
    };

    float* const b0 = lds;
    float* const b1 = lds + 8192;
    float* const b2 = lds + 16384;
    bf16x8 ac[4], an[4];

    // ---- prologue: chronological VMEM order [S0(4), A0(4), S1(4)] ----
    STAGE(0, b0);
    PREFA(ac, 0);
    STAGE(1, b1);

    // ---- main loop: tiles 0..41 ----
    // tile j: WAITV(4) drains {S(j),A(j)}, keeps S(j+1); barrier;
    //         PREFA(j+1); STAGE(j+2); COMPUTE(j).
    for (int i = 0; i < 42; i += 6) {
        WAITV(4); BARR; PREFA(an, i + 1); STAGE(i + 2, b2); COMPUTE(ac, b0);
        WAITV(4); BARR; PREFA(ac, i + 2); STAGE(i + 3, b0); COMPUTE(an, b1);
        WAITV(4); BARR; PREFA(an, i + 3); STAGE(i + 4, b1); COMPUTE(ac, b2);
        WAITV(4); BARR; PREFA(ac, i + 4); STAGE(i + 5, b2); COMPUTE(an, b0);
        WAITV(4); BARR; PREFA(an, i + 5); STAGE(i + 6, b0); COMPUTE(ac, b1);
        WAITV(4); BARR; PREFA(ac, i + 6); STAGE(i + 7, b1); COMPUTE(an, b2);
    }

    // ---- tail: tiles 42 (b0, ac), 43 (b1, an) ----
    WAITV(4); BARR; PREFA(an, 43); COMPUTE(ac, b0);
    WAITV(0); BARR; COMPUTE(an, b1);

    // ---- store (nontemporal): o = fo*16+kg*4+rr, t = tq*256+wave*32+m*16+tcol
    float* yp = y + (size_t)b * (O_ * T_) + tq * 256 + wave * 32 + tcol;
#pragma unroll
    for (int m = 0; m < 2; ++m)
#pragma unroll
        for (int fo = 0; fo < 4; ++fo)
#pragma unroll
            for (int rr = 0; rr < 4; ++rr) {
                int o = fo * 16 + kg * 4 + rr;
                __builtin_nontemporal_store(acc[m][fo][rr] + constv[o],
                                            yp + (size_t)o * T_ + m * 16);
            }
}

// ---------------------------------------------------------------------------
extern "C" void kernel_launch(void* const* d_in, const int* in_sizes, int n_in,
                              void* d_out, int out_size, void* d_ws, size_t ws_size,
                              hipStream_t stream)
{
    (void)in_sizes; (void)n_in; (void)out_size; (void)ws_size;
    const float* x     = (const float*)d_in[0];
    const float* adjp  = (const float*)d_in[1];
    const float* chebw = (const float*)d_in[2];
    const float* chebb = (const float*)d_in[3];
    const float* aggw  = (const float*)d_in[4];
    const float* aggb  = (const float*)d_in[5];
    float* y = (float*)d_out;

    char* ws = (char*)d_ws;
    float*  constv = (float*)(ws);                 // 64 floats
    __bf16* Mfrag  = (__bf16*)(ws + 4096);         // 90112 bf16 (180224 B)

    hipLaunchKernelGGL(prep_all, dim3(256), dim3(256), 0, stream,
                       adjp, chebw, chebb, aggw, aggb, Mfrag, constv);
    hipLaunchKernelGGL(gemm_main, dim3(256), dim3(512), 0, stream,
                       x, Mfrag, constv, y);
}